// Round 13
// baseline (505.841 us; speedup 1.0000x reference)
//
#include <hip/hip_runtime.h>
#include <hip/hip_bf16.h>

#define NNODES 100000
#define NEDGES 1600000
#define IND 128
#define HD 64
#define OUTD 2
#define NG 64
#define BINSHIFT 9
#define BINSZ 512            // nodes per bin
#define BSTRIDE 12288        // edge slots per bin (1.5x Poisson mean, 45 sigma)
#define PB 256               // partition blocks

typedef __attribute__((ext_vector_type(8))) short short8v;
typedef __attribute__((ext_vector_type(4))) float floatx4;

static __device__ __forceinline__ unsigned short f2bf(float f) {
    __hip_bfloat16 h = __float2bfloat16(f);
    return *(unsigned short*)&h;
}
static __device__ __forceinline__ float bf2f(unsigned short u) {
    __hip_bfloat16 h = *(__hip_bfloat16*)&u;
    return __bfloat162float(h);
}

// ============ single-pass binned edge partition ============
// dst cached in registers between histogram and partition passes (read once).
__global__ __launch_bounds__(256) void binP_kernel(const int* __restrict__ src,
                                                   const int* __restrict__ dst,
                                                   int* __restrict__ binCount,
                                                   unsigned int* __restrict__ binned,
                                                   int E, int nbins) {
    __shared__ int lh[256];
    __shared__ int lbase[256];
    int t = threadIdx.x;
    lh[t] = 0;
    __syncthreads();
    int ebpb = (E + PB - 1) / PB;
    int e0 = blockIdx.x * ebpb;
    int e1 = min(e0 + ebpb, E);
    int dcache[25];                      // ceil(6250/256) = 25
    int ec = 0;
    for (int e = e0 + t; e < e1; e += 256) {
        int d = dst[e];
        dcache[ec++] = d;
        atomicAdd(&lh[d >> BINSHIFT], 1);
    }
    __syncthreads();
    int c = lh[t];
    if (t < nbins && c > 0) lbase[t] = atomicAdd(&binCount[t], c);
    lh[t] = 0;                           // reuse as local cursor
    __syncthreads();
    ec = 0;
    for (int e = e0 + t; e < e1; e += 256) {
        int d = dcache[ec++];
        int b = d >> BINSHIFT;
        int idx = atomicAdd(&lh[b], 1);
        binned[(size_t)b * BSTRIDE + lbase[b] + idx] =
            ((unsigned int)(d & (BINSZ - 1)) << 17) | (unsigned int)src[e];
    }
}

// HD: one block per bin. histogram -> dinv -> LDS exclusive scan ->
// packed rowinfo = (start<<10)|deg -> CSR scatter with LDS countdown.
__global__ __launch_bounds__(256) void binHD_kernel(const unsigned int* __restrict__ binned,
                                                    const int* __restrict__ binCount,
                                                    float* __restrict__ dinv,
                                                    unsigned int* __restrict__ rowinfo,
                                                    int* __restrict__ ssrc, int n) {
    __shared__ int dh[BINSZ];
    __shared__ int rp[BINSZ];
    __shared__ int wsum[4];
    int b = blockIdx.x, t = threadIdx.x;
    int lane = t & 63, wv = t >> 6;
    dh[t] = 0; dh[t + 256] = 0;
    __syncthreads();
    int s0 = b * BSTRIDE;
    int cnt = binCount[b];
    for (int i = t; i < cnt; i += 256)
        atomicAdd(&dh[binned[s0 + i] >> 17], 1);
    __syncthreads();
    // dinv (deg + self loop)
#pragma unroll
    for (int r = 0; r < 2; r++) {
        int i = t + r * 256;
        int node = (b << BINSHIFT) + i;
        if (node < n) dinv[node] = 1.0f / sqrtf((float)(dh[i] + 1));
    }
    // exclusive scan of dh[0..511]; thread t owns elements 2t, 2t+1
    int d0 = dh[2 * t], d1 = dh[2 * t + 1];
    int p = d0 + d1;
    int sc = p;
#pragma unroll
    for (int d = 1; d < 64; d <<= 1) { int v = __shfl_up(sc, d, 64); if (lane >= d) sc += v; }
    if (lane == 63) wsum[wv] = sc;
    __syncthreads();
    int add = 0;
    for (int w2 = 0; w2 < wv; w2++) add += wsum[w2];
    int ex = sc - p + add;
    rp[2 * t]     = ex;
    rp[2 * t + 1] = ex + d0;
    __syncthreads();
    // packed rowinfo (start < 2^22, deg capped at 1023)
#pragma unroll
    for (int r = 0; r < 2; r++) {
        int i = t + r * 256;
        int node = (b << BINSHIFT) + i;
        if (node < n)
            rowinfo[node] = ((unsigned int)(s0 + rp[i]) << 10) |
                            (unsigned int)min(dh[i], 1023);
    }
    __syncthreads();
    // scatter (dh consumed as countdown)
    for (int i = t; i < cnt; i += 256) {
        unsigned int rec = binned[s0 + i];
        int doff = rec >> 17;
        int s = rec & 0x1FFFF;
        int idx = atomicSub(&dh[doff], 1) - 1;
        ssrc[s0 + rp[doff] + idx] = s;
    }
}

// ---------------- prep: W1 transpose (bf16) + gcnt batch histogram ---------
__global__ __launch_bounds__(256) void prep_kernel(const float* __restrict__ W1,
                                                   unsigned short* __restrict__ WT1,
                                                   const int* __restrict__ batch,
                                                   float* __restrict__ gcnt, int n) {
    int blk = blockIdx.x;
    if (blk < 32) {
        int i = blk * 256 + threadIdx.x;   // 64*128 = 8192 elems
        int nn2 = i / IND, k = i - nn2 * IND;
        WT1[i] = f2bf(W1[k * 64 + nn2]);
    } else {
        __shared__ float lg[NG];
        int t = threadIdx.x;
        if (t < NG) lg[t] = 0.f;
        __syncthreads();
        int nb2 = gridDim.x - 32;
        int per = (n + nb2 - 1) / nb2;
        int i0 = (blk - 32) * per;
        int i1 = min(i0 + per, n);
        for (int i = i0 + t; i < i1; i += 256)
            atomicAdd(&lg[batch[i]], 1.f);
        __syncthreads();
        if (t < NG) atomicAdd(&gcnt[t], lg[t]);
    }
}

// ---------------- MFMA matmul: Tb[n][:] = bf16( dinv[n] * (X[n,:K] @ W) ) --
template <int K, bool BF16IN>
__global__ __launch_bounds__(256) void mm_mfma_kernel(const void* __restrict__ Xv,
                                                      const unsigned short* __restrict__ WT,
                                                      const float* __restrict__ dinv,
                                                      unsigned short* __restrict__ Tb, int nn) {
    const int lane = threadIdx.x & 63;
    const int wv   = threadIdx.x >> 6;
    const int nb   = blockIdx.x * 64 + wv * 16;
    if (nb >= nn) return;
    const int col  = lane & 15;
    const int quad = lane >> 4;
    const int m    = min(nb + col, nn - 1);

    floatx4 acc0 = {0.f, 0.f, 0.f, 0.f};
    floatx4 acc1 = {0.f, 0.f, 0.f, 0.f};
    floatx4 acc2 = {0.f, 0.f, 0.f, 0.f};
    floatx4 acc3 = {0.f, 0.f, 0.f, 0.f};

#pragma unroll
    for (int ks = 0; ks < K; ks += 32) {
        const int k0 = ks + quad * 8;
        short8v a;
        if (BF16IN) {
            a = *(const short8v*)((const unsigned short*)Xv + (size_t)m * K + k0);
        } else {
            const float* xr = (const float*)Xv + (size_t)m * K + k0;
            float4 f0 = *(const float4*)(xr);
            float4 f1 = *(const float4*)(xr + 4);
            a[0] = (short)f2bf(f0.x); a[1] = (short)f2bf(f0.y);
            a[2] = (short)f2bf(f0.z); a[3] = (short)f2bf(f0.w);
            a[4] = (short)f2bf(f1.x); a[5] = (short)f2bf(f1.y);
            a[6] = (short)f2bf(f1.z); a[7] = (short)f2bf(f1.w);
        }
        short8v b0 = *(const short8v*)(WT + (size_t)(0  + col) * K + k0);
        short8v b1 = *(const short8v*)(WT + (size_t)(16 + col) * K + k0);
        short8v b2 = *(const short8v*)(WT + (size_t)(32 + col) * K + k0);
        short8v b3 = *(const short8v*)(WT + (size_t)(48 + col) * K + k0);
        acc0 = __builtin_amdgcn_mfma_f32_16x16x32_bf16(a, b0, acc0, 0, 0, 0);
        acc1 = __builtin_amdgcn_mfma_f32_16x16x32_bf16(a, b1, acc1, 0, 0, 0);
        acc2 = __builtin_amdgcn_mfma_f32_16x16x32_bf16(a, b2, acc2, 0, 0, 0);
        acc3 = __builtin_amdgcn_mfma_f32_16x16x32_bf16(a, b3, acc3, 0, 0, 0);
    }

#pragma unroll
    for (int r = 0; r < 4; r++) {
        int node = nb + quad * 4 + r;
        if (node < nn) {
            float sc = dinv[node];
            unsigned short* o = Tb + (size_t)node * 64 + col;
            o[0]  = f2bf(sc * acc0[r]);
            o[16] = f2bf(sc * acc1[r]);
            o[32] = f2bf(sc * acc2[r]);
            o[48] = f2bf(sc * acc3[r]);
        }
    }
}

// ---------------- pull aggregation (16-deep) + optional fused next-matmul --
// FUSE=true: after computing the relu'd row o (fp32, lane=feature), compute
// t_next[n][j] = dinv[n] * sum_k o[k] * Wn[k][j] via __shfl broadcast of o
// and Wn staged in LDS (fp32, 16 KB) -- deletes the standalone mm dispatch
// and the bf16 round-trip through hBb (o stays fp32 into the matmul).
template <bool FUSE>
__global__ __launch_bounds__(256) void agg_kernel(const unsigned short* __restrict__ Tb,
                                                  const unsigned int* __restrict__ rowinfo,
                                                  const int* __restrict__ ssrc,
                                                  const float* __restrict__ dinv,
                                                  const float* __restrict__ bias,
                                                  const float* __restrict__ Wn,
                                                  unsigned short* __restrict__ Out, int nn) {
    __shared__ float Wl[64 * 64];
    if (FUSE) {
        for (int i = threadIdx.x; i < 64 * 16; i += 256)
            ((float4*)Wl)[i] = ((const float4*)Wn)[i];
        __syncthreads();
    }
    int wave = __builtin_amdgcn_readfirstlane((blockIdx.x * 256 + threadIdx.x) >> 6);
    int lane = threadIdx.x & 63;
    if (wave >= nn) return;
    int n = wave;
    float acc = bf2f(Tb[(size_t)n * 64 + lane]);   // self loop (pre-scaled row)
    unsigned int info = rowinfo[n];
    int rb = (int)(info >> 10);
    int re = rb + (int)(info & 1023);
    int i = rb;
    for (; i + 16 <= re; i += 16) {
        int s[16];
#pragma unroll
        for (int k = 0; k < 16; k++) s[k] = ssrc[i + k];
        float v[16];
#pragma unroll
        for (int k = 0; k < 16; k++) v[k] = bf2f(Tb[(size_t)s[k] * 64 + lane]);
#pragma unroll
        for (int k = 0; k < 16; k++) acc += v[k];
    }
    for (; i + 4 <= re; i += 4) {
        int s0 = ssrc[i], s1 = ssrc[i + 1], s2 = ssrc[i + 2], s3 = ssrc[i + 3];
        float v0 = bf2f(Tb[(size_t)s0 * 64 + lane]);
        float v1 = bf2f(Tb[(size_t)s1 * 64 + lane]);
        float v2 = bf2f(Tb[(size_t)s2 * 64 + lane]);
        float v3 = bf2f(Tb[(size_t)s3 * 64 + lane]);
        acc += v0; acc += v1; acc += v2; acc += v3;
    }
    for (; i < re; i++)
        acc += bf2f(Tb[(size_t)ssrc[i] * 64 + lane]);
    float dn = dinv[n];
    float o = dn * acc + bias[lane];
    o = o > 0.f ? o : 0.f;
    if (FUSE) {
        float tacc = 0.f;
#pragma unroll 16
        for (int k = 0; k < 64; k++) {
            float ok = __shfl(o, k, 64);
            tacc += ok * Wl[k * 64 + lane];
        }
        Out[(size_t)n * 64 + lane] = f2bf(dn * tacc);
    } else {
        Out[(size_t)n * 64 + lane] = f2bf(o);
    }
}

// ---------------- mean pool (bf16 input): sorted-run register accumulation -
__global__ __launch_bounds__(256) void pool_kernel(const unsigned short* __restrict__ Hb,
                                                   const int* __restrict__ batch,
                                                   float* __restrict__ pooled, int nn) {
    int wid = (blockIdx.x * 256 + threadIdx.x) >> 6;
    int lane = threadIdx.x & 63;
    int nwaves = (gridDim.x * 256) >> 6;
    int per = (nn + nwaves - 1) / nwaves;
    int n0 = wid * per;
    int n1 = n0 + per; if (n1 > nn) n1 = nn;
    if (n0 >= n1) return;
    int cur = batch[n0];
    float acc = 0.f;
    for (int n = n0; n < n1; ++n) {
        int g = batch[n];
        if (g != cur) {
            atomicAdd(&pooled[cur * 64 + lane], acc);
            acc = 0.f; cur = g;
        }
        acc += bf2f(Hb[(size_t)n * 64 + lane]);
    }
    atomicAdd(&pooled[cur * 64 + lane], acc);
}

// ---------------- MLP head (single block) ----------------
__global__ __launch_bounds__(256) void head_kernel(const float* __restrict__ pooled,
                                                   const float* __restrict__ gcnt,
                                                   const float* __restrict__ Wm1,
                                                   const float* __restrict__ bm1,
                                                   const float* __restrict__ Wm2,
                                                   const float* __restrict__ bm2,
                                                   float* __restrict__ out) {
    __shared__ float P[NG * 64];
    __shared__ float Z[NG * 64];
    int tid = threadIdx.x;
    for (int i = tid; i < NG * 64; i += 256) {
        int g = i >> 6;
        float c = gcnt[g];
        c = c > 1.f ? c : 1.f;
        P[i] = pooled[i] / c;
    }
    __syncthreads();
    for (int i = tid; i < NG * 64; i += 256) {
        int g = i >> 6, j = i & 63;
        float a = bm1[j];
#pragma unroll 8
        for (int k = 0; k < 64; ++k) a += P[g * 64 + k] * Wm1[k * 64 + j];
        Z[i] = a > 0.f ? a : 0.f;
    }
    __syncthreads();
    for (int i = tid; i < NG * OUTD; i += 256) {
        int g = i / OUTD, o = i % OUTD;
        float a = bm2[o];
#pragma unroll 8
        for (int k = 0; k < 64; ++k) a += Z[g * 64 + k] * Wm2[k * OUTD + o];
        out[i] = a;
    }
}

extern "C" void kernel_launch(void* const* d_in, const int* in_sizes, int n_in,
                              void* d_out, int out_size, void* d_ws, size_t ws_size,
                              hipStream_t stream) {
    const float* x    = (const float*)d_in[0];
    const int*  edge  = (const int*)d_in[1];
    const int*  batch = (const int*)d_in[2];
    const float* W1 = (const float*)d_in[3];
    const float* b1 = (const float*)d_in[4];
    const float* W2 = (const float*)d_in[5];
    const float* b2 = (const float*)d_in[6];
    const float* W3 = (const float*)d_in[7];
    const float* b3 = (const float*)d_in[8];
    const float* Wm1 = (const float*)d_in[9];
    const float* bm1 = (const float*)d_in[10];
    const float* Wm2 = (const float*)d_in[11];
    const float* bm2 = (const float*)d_in[12];

    const int N_ = in_sizes[2];           // 100000
    const int E_ = in_sizes[1] / 2;       // 1600000
    const int* src = edge;
    const int* dst = edge + E_;
    const int nbins = (N_ + BINSZ - 1) >> BINSHIFT;   // 196

    // workspace carve (256 B aligned)
    char* w = (char*)d_ws;
    auto alloc = [&](size_t bytes) -> void* {
        void* p = (void*)w;
        w += (bytes + 255) & ~(size_t)255;
        return p;
    };
    float* dinv   = (float*)alloc((size_t)N_ * 4);
    unsigned int* rowinfo = (unsigned int*)alloc((size_t)N_ * 4);
    float* pooled = (float*)alloc((size_t)(NG * 64 + NG) * 4);   // 16640 B
    int*   binCount = (int*)alloc(256 * 4);                      // adjacent to pooled
    float* gcnt   = pooled + NG * 64;
    int*   ssrc   = (int*)alloc((size_t)nbins * BSTRIDE * 4);
    unsigned int* binned = (unsigned int*)alloc((size_t)nbins * BSTRIDE * 4);
    unsigned short* Tb  = (unsigned short*)alloc((size_t)N_ * 64 * 2);
    unsigned short* Tb2 = (unsigned short*)alloc((size_t)N_ * 64 * 2);
    unsigned short* hBb = (unsigned short*)alloc((size_t)N_ * 64 * 2);
    unsigned short* WT1 = (unsigned short*)alloc((size_t)64 * IND * 2);

    // zero pooled + gcnt + binCount in one shot (contiguous carve)
    hipMemsetAsync(pooled, 0, (size_t)(NG * 64 + NG) * 4 + 256 * 4 + 256, stream);

    // ---- CSR build: 2 dispatches ----
    binP_kernel<<<PB, 256, 0, stream>>>(src, dst, binCount, binned, E_, nbins);
    binHD_kernel<<<nbins, 256, 0, stream>>>(binned, binCount, dinv, rowinfo, ssrc, N_);

    // ---- prep: WT1 + gcnt (1 dispatch) ----
    prep_kernel<<<32 + 16, 256, 0, stream>>>(W1, WT1, batch, gcnt, N_);

    const int mmblk = (N_ + 63) / 64;             // 64 nodes per block (4 waves x 16)
    const int aggblk = (N_ + 3) / 4;              // 4 waves (nodes) per block

    // layer 1 matmul (MFMA, x fp32 -> Tb)
    mm_mfma_kernel<IND, false><<<mmblk, 256, 0, stream>>>(x, WT1, dinv, Tb, N_);
    // agg1 + fused W2 matmul  (Tb -> Tb2)
    agg_kernel<true><<<aggblk, 256, 0, stream>>>(Tb, rowinfo, ssrc, dinv, b1, W2, Tb2, N_);
    // agg2 + fused W3 matmul  (Tb2 -> Tb)
    agg_kernel<true><<<aggblk, 256, 0, stream>>>(Tb2, rowinfo, ssrc, dinv, b2, W3, Tb, N_);
    // agg3 (plain)            (Tb -> hBb)
    agg_kernel<false><<<aggblk, 256, 0, stream>>>(Tb, rowinfo, ssrc, dinv, b3, nullptr, hBb, N_);

    // pool + head
    pool_kernel<<<256, 256, 0, stream>>>(hBb, batch, pooled, N_);
    head_kernel<<<1, 256, 0, stream>>>(pooled, gcnt, Wm1, bm1, Wm2, bm2, (float*)d_out);
}

// Round 14
// 384.302 us; speedup vs baseline: 1.3163x; 1.3163x over previous
//
#include <hip/hip_runtime.h>
#include <hip/hip_bf16.h>

#define NNODES 100000
#define NEDGES 1600000
#define IND 128
#define HD 64
#define OUTD 2
#define NG 64
#define BINSHIFT 9
#define BINSZ 512            // nodes per bin
#define BSTRIDE 12288        // edge slots per bin (1.5x Poisson mean, 45 sigma)
#define PB 256               // partition blocks

typedef __attribute__((ext_vector_type(8))) short short8v;
typedef __attribute__((ext_vector_type(4))) float floatx4;

static __device__ __forceinline__ unsigned short f2bf(float f) {
    __hip_bfloat16 h = __float2bfloat16(f);
    return *(unsigned short*)&h;
}
static __device__ __forceinline__ float bf2f(unsigned short u) {
    __hip_bfloat16 h = *(__hip_bfloat16*)&u;
    return __bfloat162float(h);
}

// ============ single-pass binned edge partition (1024 thr: 16 waves/CU) ====
// dst cached in registers between histogram and partition passes (read once).
__global__ __launch_bounds__(1024) void binP_kernel(const int* __restrict__ src,
                                                    const int* __restrict__ dst,
                                                    int* __restrict__ binCount,
                                                    unsigned int* __restrict__ binned,
                                                    int E, int nbins) {
    __shared__ int lh[256];
    __shared__ int lbase[256];
    int t = threadIdx.x;
    if (t < 256) lh[t] = 0;
    __syncthreads();
    int ebpb = (E + PB - 1) / PB;
    int e0 = blockIdx.x * ebpb;
    int e1 = min(e0 + ebpb, E);
    int dcache[8];                       // ceil(6250/1024) = 7
    int ec = 0;
    for (int e = e0 + t; e < e1; e += 1024) {
        int d = dst[e];
        dcache[ec++] = d;
        atomicAdd(&lh[d >> BINSHIFT], 1);
    }
    __syncthreads();
    if (t < nbins) {
        int c = lh[t];
        if (c > 0) lbase[t] = atomicAdd(&binCount[t], c);
        lh[t] = 0;                       // reuse as local cursor
    }
    __syncthreads();
    ec = 0;
    for (int e = e0 + t; e < e1; e += 1024) {
        int d = dcache[ec++];
        int b = d >> BINSHIFT;
        int idx = atomicAdd(&lh[b], 1);
        binned[(size_t)b * BSTRIDE + lbase[b] + idx] =
            ((unsigned int)(d & (BINSZ - 1)) << 17) | (unsigned int)src[e];
    }
}

// HD (1024 thr): one block per bin. histogram -> dinv -> LDS exclusive scan
// (threads 0..255, convergent barriers) -> packed rowinfo = (start<<10)|deg
// -> CSR scatter with LDS countdown.
__global__ __launch_bounds__(1024) void binHD_kernel(const unsigned int* __restrict__ binned,
                                                     const int* __restrict__ binCount,
                                                     float* __restrict__ dinv,
                                                     unsigned int* __restrict__ rowinfo,
                                                     int* __restrict__ ssrc, int n) {
    __shared__ int dh[BINSZ];
    __shared__ int rp[BINSZ];
    __shared__ int wsum[4];
    int b = blockIdx.x, t = threadIdx.x;
    int lane = t & 63, wv = t >> 6;
    if (t < BINSZ) dh[t] = 0;
    __syncthreads();
    int s0 = b * BSTRIDE;
    int cnt = binCount[b];
    for (int i = t; i < cnt; i += 1024)
        atomicAdd(&dh[binned[s0 + i] >> 17], 1);
    __syncthreads();
    // dinv (deg + self loop)
    if (t < BINSZ) {
        int node = (b << BINSHIFT) + t;
        if (node < n) dinv[node] = 1.0f / sqrtf((float)(dh[t] + 1));
    }
    // exclusive scan of dh[0..511] by threads 0..255 (2 elems each);
    // all threads participate in barriers (waves 4..15 compute garbage shfl)
    int d0 = 0, d1 = 0, p = 0;
    if (t < 256) { d0 = dh[2 * t]; d1 = dh[2 * t + 1]; p = d0 + d1; }
    int sc = p;
#pragma unroll
    for (int d = 1; d < 64; d <<= 1) { int v = __shfl_up(sc, d, 64); if (lane >= d) sc += v; }
    if (t < 256 && lane == 63) wsum[wv] = sc;
    __syncthreads();
    if (t < 256) {
        int add = 0;
        for (int w2 = 0; w2 < wv; w2++) add += wsum[w2];
        int ex = sc - p + add;
        rp[2 * t]     = ex;
        rp[2 * t + 1] = ex + d0;
    }
    __syncthreads();
    // packed rowinfo (start < 2^22, deg capped at 1023)
    if (t < BINSZ) {
        int node = (b << BINSHIFT) + t;
        if (node < n)
            rowinfo[node] = ((unsigned int)(s0 + rp[t]) << 10) |
                            (unsigned int)min(dh[t], 1023);
    }
    __syncthreads();
    // scatter (dh consumed as countdown)
    for (int i = t; i < cnt; i += 1024) {
        unsigned int rec = binned[s0 + i];
        int doff = rec >> 17;
        int s = rec & 0x1FFFF;
        int idx = atomicSub(&dh[doff], 1) - 1;
        ssrc[s0 + rp[doff] + idx] = s;
    }
}

// ---------------- prep: 3 W transposes + gcnt batch histogram --------------
__global__ __launch_bounds__(256) void prep_kernel(const float* __restrict__ W1,
                                                   const float* __restrict__ W2,
                                                   const float* __restrict__ W3,
                                                   unsigned short* __restrict__ WT1,
                                                   unsigned short* __restrict__ WT2,
                                                   unsigned short* __restrict__ WT3,
                                                   const int* __restrict__ batch,
                                                   float* __restrict__ gcnt, int n) {
    int blk = blockIdx.x;
    if (blk < 64) {
        int i = blk * 256 + threadIdx.x;
        if (i < 64 * IND) {
            int nn2 = i / IND, k = i - nn2 * IND;
            WT1[i] = f2bf(W1[k * 64 + nn2]);
        } else if (i < 64 * IND + 64 * HD) {
            int j = i - 64 * IND;
            int nn2 = j / HD, k = j - nn2 * HD;
            WT2[j] = f2bf(W2[k * 64 + nn2]);
        } else {
            int j = i - 64 * IND - 64 * HD;
            int nn2 = j / HD, k = j - nn2 * HD;
            WT3[j] = f2bf(W3[k * 64 + nn2]);
        }
    } else {
        __shared__ float lg[NG];
        int t = threadIdx.x;
        if (t < NG) lg[t] = 0.f;
        __syncthreads();
        int nb2 = gridDim.x - 64;
        int per = (n + nb2 - 1) / nb2;
        int i0 = (blk - 64) * per;
        int i1 = min(i0 + per, n);
        for (int i = i0 + t; i < i1; i += 256)
            atomicAdd(&lg[batch[i]], 1.f);
        __syncthreads();
        if (t < NG) atomicAdd(&gcnt[t], lg[t]);
    }
}

// ---------------- MFMA matmul: Tb[n][:] = bf16( dinv[n] * (X[n,:K] @ W) ) --
template <int K, bool BF16IN>
__global__ __launch_bounds__(256) void mm_mfma_kernel(const void* __restrict__ Xv,
                                                      const unsigned short* __restrict__ WT,
                                                      const float* __restrict__ dinv,
                                                      unsigned short* __restrict__ Tb, int nn) {
    const int lane = threadIdx.x & 63;
    const int wv   = threadIdx.x >> 6;
    const int nb   = blockIdx.x * 64 + wv * 16;
    if (nb >= nn) return;
    const int col  = lane & 15;
    const int quad = lane >> 4;
    const int m    = min(nb + col, nn - 1);

    floatx4 acc0 = {0.f, 0.f, 0.f, 0.f};
    floatx4 acc1 = {0.f, 0.f, 0.f, 0.f};
    floatx4 acc2 = {0.f, 0.f, 0.f, 0.f};
    floatx4 acc3 = {0.f, 0.f, 0.f, 0.f};

#pragma unroll
    for (int ks = 0; ks < K; ks += 32) {
        const int k0 = ks + quad * 8;
        short8v a;
        if (BF16IN) {
            a = *(const short8v*)((const unsigned short*)Xv + (size_t)m * K + k0);
        } else {
            const float* xr = (const float*)Xv + (size_t)m * K + k0;
            float4 f0 = *(const float4*)(xr);
            float4 f1 = *(const float4*)(xr + 4);
            a[0] = (short)f2bf(f0.x); a[1] = (short)f2bf(f0.y);
            a[2] = (short)f2bf(f0.z); a[3] = (short)f2bf(f0.w);
            a[4] = (short)f2bf(f1.x); a[5] = (short)f2bf(f1.y);
            a[6] = (short)f2bf(f1.z); a[7] = (short)f2bf(f1.w);
        }
        short8v b0 = *(const short8v*)(WT + (size_t)(0  + col) * K + k0);
        short8v b1 = *(const short8v*)(WT + (size_t)(16 + col) * K + k0);
        short8v b2 = *(const short8v*)(WT + (size_t)(32 + col) * K + k0);
        short8v b3 = *(const short8v*)(WT + (size_t)(48 + col) * K + k0);
        acc0 = __builtin_amdgcn_mfma_f32_16x16x32_bf16(a, b0, acc0, 0, 0, 0);
        acc1 = __builtin_amdgcn_mfma_f32_16x16x32_bf16(a, b1, acc1, 0, 0, 0);
        acc2 = __builtin_amdgcn_mfma_f32_16x16x32_bf16(a, b2, acc2, 0, 0, 0);
        acc3 = __builtin_amdgcn_mfma_f32_16x16x32_bf16(a, b3, acc3, 0, 0, 0);
    }

#pragma unroll
    for (int r = 0; r < 4; r++) {
        int node = nb + quad * 4 + r;
        if (node < nn) {
            float sc = dinv[node];
            unsigned short* o = Tb + (size_t)node * 64 + col;
            o[0]  = f2bf(sc * acc0[r]);
            o[16] = f2bf(sc * acc1[r]);
            o[32] = f2bf(sc * acc2[r]);
            o[48] = f2bf(sc * acc3[r]);
        }
    }
}

// ---------------- pull aggregation, 16-deep gather pipeline ----------------
__global__ __launch_bounds__(256) void agg_kernel(const unsigned short* __restrict__ Tb,
                                                  const unsigned int* __restrict__ rowinfo,
                                                  const int* __restrict__ ssrc,
                                                  const float* __restrict__ dinv,
                                                  const float* __restrict__ bias,
                                                  unsigned short* __restrict__ Ob, int nn) {
    int wave = __builtin_amdgcn_readfirstlane((blockIdx.x * 256 + threadIdx.x) >> 6);
    int lane = threadIdx.x & 63;
    if (wave >= nn) return;
    int n = wave;
    float acc = bf2f(Tb[(size_t)n * 64 + lane]);   // self loop (pre-scaled row)
    unsigned int info = rowinfo[n];
    int rb = (int)(info >> 10);
    int re = rb + (int)(info & 1023);
    int i = rb;
    for (; i + 16 <= re; i += 16) {
        int s[16];
#pragma unroll
        for (int k = 0; k < 16; k++) s[k] = ssrc[i + k];
        float v[16];
#pragma unroll
        for (int k = 0; k < 16; k++) v[k] = bf2f(Tb[(size_t)s[k] * 64 + lane]);
#pragma unroll
        for (int k = 0; k < 16; k++) acc += v[k];
    }
    for (; i + 4 <= re; i += 4) {
        int s0 = ssrc[i], s1 = ssrc[i + 1], s2 = ssrc[i + 2], s3 = ssrc[i + 3];
        float v0 = bf2f(Tb[(size_t)s0 * 64 + lane]);
        float v1 = bf2f(Tb[(size_t)s1 * 64 + lane]);
        float v2 = bf2f(Tb[(size_t)s2 * 64 + lane]);
        float v3 = bf2f(Tb[(size_t)s3 * 64 + lane]);
        acc += v0; acc += v1; acc += v2; acc += v3;
    }
    for (; i < re; i++)
        acc += bf2f(Tb[(size_t)ssrc[i] * 64 + lane]);
    float o = dinv[n] * acc + bias[lane];
    o = o > 0.f ? o : 0.f;
    Ob[(size_t)n * 64 + lane] = f2bf(o);
}

// ---------------- mean pool (bf16 input): sorted-run register accumulation -
__global__ __launch_bounds__(256) void pool_kernel(const unsigned short* __restrict__ Hb,
                                                   const int* __restrict__ batch,
                                                   float* __restrict__ pooled, int nn) {
    int wid = (blockIdx.x * 256 + threadIdx.x) >> 6;
    int lane = threadIdx.x & 63;
    int nwaves = (gridDim.x * 256) >> 6;
    int per = (nn + nwaves - 1) / nwaves;
    int n0 = wid * per;
    int n1 = n0 + per; if (n1 > nn) n1 = nn;
    if (n0 >= n1) return;
    int cur = batch[n0];
    float acc = 0.f;
    for (int n = n0; n < n1; ++n) {
        int g = batch[n];
        if (g != cur) {
            atomicAdd(&pooled[cur * 64 + lane], acc);
            acc = 0.f; cur = g;
        }
        acc += bf2f(Hb[(size_t)n * 64 + lane]);
    }
    atomicAdd(&pooled[cur * 64 + lane], acc);
}

// ---------------- MLP head (single block) ----------------
__global__ __launch_bounds__(256) void head_kernel(const float* __restrict__ pooled,
                                                   const float* __restrict__ gcnt,
                                                   const float* __restrict__ Wm1,
                                                   const float* __restrict__ bm1,
                                                   const float* __restrict__ Wm2,
                                                   const float* __restrict__ bm2,
                                                   float* __restrict__ out) {
    __shared__ float P[NG * 64];
    __shared__ float Z[NG * 64];
    int tid = threadIdx.x;
    for (int i = tid; i < NG * 64; i += 256) {
        int g = i >> 6;
        float c = gcnt[g];
        c = c > 1.f ? c : 1.f;
        P[i] = pooled[i] / c;
    }
    __syncthreads();
    for (int i = tid; i < NG * 64; i += 256) {
        int g = i >> 6, j = i & 63;
        float a = bm1[j];
#pragma unroll 8
        for (int k = 0; k < 64; ++k) a += P[g * 64 + k] * Wm1[k * 64 + j];
        Z[i] = a > 0.f ? a : 0.f;
    }
    __syncthreads();
    for (int i = tid; i < NG * OUTD; i += 256) {
        int g = i / OUTD, o = i % OUTD;
        float a = bm2[o];
#pragma unroll 8
        for (int k = 0; k < 64; ++k) a += Z[g * 64 + k] * Wm2[k * OUTD + o];
        out[i] = a;
    }
}

extern "C" void kernel_launch(void* const* d_in, const int* in_sizes, int n_in,
                              void* d_out, int out_size, void* d_ws, size_t ws_size,
                              hipStream_t stream) {
    const float* x    = (const float*)d_in[0];
    const int*  edge  = (const int*)d_in[1];
    const int*  batch = (const int*)d_in[2];
    const float* W1 = (const float*)d_in[3];
    const float* b1 = (const float*)d_in[4];
    const float* W2 = (const float*)d_in[5];
    const float* b2 = (const float*)d_in[6];
    const float* W3 = (const float*)d_in[7];
    const float* b3 = (const float*)d_in[8];
    const float* Wm1 = (const float*)d_in[9];
    const float* bm1 = (const float*)d_in[10];
    const float* Wm2 = (const float*)d_in[11];
    const float* bm2 = (const float*)d_in[12];

    const int N_ = in_sizes[2];           // 100000
    const int E_ = in_sizes[1] / 2;       // 1600000
    const int* src = edge;
    const int* dst = edge + E_;
    const int nbins = (N_ + BINSZ - 1) >> BINSHIFT;   // 196

    // workspace carve (256 B aligned)
    char* w = (char*)d_ws;
    auto alloc = [&](size_t bytes) -> void* {
        void* p = (void*)w;
        w += (bytes + 255) & ~(size_t)255;
        return p;
    };
    float* dinv   = (float*)alloc((size_t)N_ * 4);
    unsigned int* rowinfo = (unsigned int*)alloc((size_t)N_ * 4);
    float* pooled = (float*)alloc((size_t)(NG * 64 + NG) * 4);   // 16640 B
    int*   binCount = (int*)alloc(256 * 4);                      // adjacent to pooled
    float* gcnt   = pooled + NG * 64;
    int*   ssrc   = (int*)alloc((size_t)nbins * BSTRIDE * 4);
    unsigned int* binned = (unsigned int*)alloc((size_t)nbins * BSTRIDE * 4);
    unsigned short* Tb  = (unsigned short*)alloc((size_t)N_ * 64 * 2);
    unsigned short* hBb = (unsigned short*)alloc((size_t)N_ * 64 * 2);
    unsigned short* WT1 = (unsigned short*)alloc((size_t)64 * IND * 2);
    unsigned short* WT2 = (unsigned short*)alloc((size_t)64 * HD * 2);
    unsigned short* WT3 = (unsigned short*)alloc((size_t)64 * HD * 2);

    // zero pooled + gcnt + binCount in one shot (contiguous carve)
    hipMemsetAsync(pooled, 0, (size_t)(NG * 64 + NG) * 4 + 256 * 4 + 256, stream);

    // ---- CSR build: 2 dispatches, 1024-thread blocks ----
    binP_kernel<<<PB, 1024, 0, stream>>>(src, dst, binCount, binned, E_, nbins);
    binHD_kernel<<<nbins, 1024, 0, stream>>>(binned, binCount, dinv, rowinfo, ssrc, N_);

    // ---- prep: weight transposes + gcnt (1 dispatch) ----
    prep_kernel<<<64 + 16, 256, 0, stream>>>(W1, W2, W3, WT1, WT2, WT3, batch, gcnt, N_);

    const int mmblk = (N_ + 63) / 64;             // 64 nodes per block (4 waves x 16)
    const int aggblk = (N_ + 3) / 4;              // 4 waves (nodes) per block

    // layer 1
    mm_mfma_kernel<IND, false><<<mmblk, 256, 0, stream>>>(x, WT1, dinv, Tb, N_);
    agg_kernel<<<aggblk, 256, 0, stream>>>(Tb, rowinfo, ssrc, dinv, b1, hBb, N_);
    // layer 2
    mm_mfma_kernel<HD, true><<<mmblk, 256, 0, stream>>>(hBb, WT2, dinv, Tb, N_);
    agg_kernel<<<aggblk, 256, 0, stream>>>(Tb, rowinfo, ssrc, dinv, b2, hBb, N_);
    // layer 3
    mm_mfma_kernel<HD, true><<<mmblk, 256, 0, stream>>>(hBb, WT3, dinv, Tb, N_);
    agg_kernel<<<aggblk, 256, 0, stream>>>(Tb, rowinfo, ssrc, dinv, b3, hBb, N_);

    // pool + head
    pool_kernel<<<256, 256, 0, stream>>>(hBb, batch, pooled, N_);
    head_kernel<<<1, 256, 0, stream>>>(pooled, gcnt, Wm1, bm1, Wm2, bm2, (float*)d_out);
}